// Round 1
// baseline (514.866 us; speedup 1.0000x reference)
//
#include <hip/hip_runtime.h>
#include <math.h>

// Problem constants (from reference)
#define NB 32
#define NH 32
#define NKV 8
#define NG 4          // H / HKV
#define DH 128
#define MAXL 2048
#define CHUNK 256
#define NCH (MAXL / CHUNK)   // 8

// (1/sqrt(128)) * log2(e) so we can use exp2f (native v_exp_f32)
#define SCALE_LOG2E 0.12752966529379885f

// Kernel 1: per-(batch, kv-head, chunk) partial flash attention.
// Block = 256 threads = 4 waves; each wave handles 64 positions of the
// 256-position chunk; within a wave, lanes 0-31 / 32-63 each handle one
// position per iteration (32 lanes x float4 = one 512B KV row, coalesced).
__global__ __launch_bounds__(256) void attn_partial_kernel(
    const float* __restrict__ q,
    const float* __restrict__ knew,
    const float* __restrict__ vnew,
    const float* __restrict__ kcache,
    const float* __restrict__ vcache,
    const int* __restrict__ base_offsets,
    const int* __restrict__ live_counts,
    const int* __restrict__ slot_mapping,
    float* __restrict__ pml,    // [NB*NKV*NG*NCH][2]  (m, l)
    float* __restrict__ pacc)   // [NB*NKV*NG*NCH][DH] unnormalized acc
{
    const int c = blockIdx.x;   // chunk
    const int h = blockIdx.y;   // kv head
    const int b = blockIdx.z;   // batch

    const int live = live_counts[b];
    const int p0 = c * CHUNK;
    if (p0 >= live) return;     // block-uniform early exit

    const int base = base_offsets[b];
    const int slot = slot_mapping[b];

    const int tid  = (int)threadIdx.x;
    const int wave = tid >> 6;
    const int lane = tid & 63;
    const int half = lane >> 5;  // which position of the pair
    const int ql   = lane & 31;  // which float4 of the 128-dim row

    // Q fragments for the 4 grouped query heads (held in registers)
    float4 qv[NG];
#pragma unroll
    for (int g = 0; g < NG; ++g)
        qv[g] = *(const float4*)(q + (size_t)(b * NH + h * NG + g) * DH + ql * 4);

    float m[NG], l[NG];
    float4 acc[NG];
#pragma unroll
    for (int g = 0; g < NG; ++g) {
        m[g] = -INFINITY;
        l[g] = 0.f;
        acc[g] = make_float4(0.f, 0.f, 0.f, 0.f);
    }

    const size_t rowstride = (size_t)NKV * DH;   // floats between positions
    const float* kbase = kcache + ((size_t)base * NKV + h) * DH + ql * 4;
    const float* vbase = vcache + ((size_t)base * NKV + h) * DH + ql * 4;

    const int pw0 = p0 + wave * 64;
    const int rem = live - pw0;
    const int iters = (rem <= 0) ? 0 : (rem >= 64 ? 32 : ((rem + 1) >> 1));

    int p = pw0 + half;
    float4 kv = make_float4(0.f, 0.f, 0.f, 0.f), vv = kv;
    if (p < live) {
        kv = *(const float4*)(kbase + (size_t)p * rowstride);
        vv = *(const float4*)(vbase + (size_t)p * rowstride);
    }

    for (int i = 0; i < iters; ++i) {
        // prefetch next pair (keeps >=2 loads outstanding per wave)
        const int pn = p + 2;
        float4 kn = make_float4(0.f, 0.f, 0.f, 0.f), vn = kn;
        if (i + 1 < iters && pn < live) {
            kn = *(const float4*)(kbase + (size_t)pn * rowstride);
            vn = *(const float4*)(vbase + (size_t)pn * rowstride);
        }

        if (p < live) {                       // uniform per 32-lane half
            float4 kk = kv, vx = vv;
            if (base + p == slot) {           // the freshly-scattered token
                kk = *(const float4*)(knew + (size_t)(b * NKV + h) * DH + ql * 4);
                vx = *(const float4*)(vnew + (size_t)(b * NKV + h) * DH + ql * 4);
            }
#pragma unroll
            for (int g = 0; g < NG; ++g) {
                float d = kk.x * qv[g].x + kk.y * qv[g].y +
                          kk.z * qv[g].z + kk.w * qv[g].w;
                // reduce across the 32 lanes of this half (xor<=16 stays inside)
                d += __shfl_xor(d, 1);
                d += __shfl_xor(d, 2);
                d += __shfl_xor(d, 4);
                d += __shfl_xor(d, 8);
                d += __shfl_xor(d, 16);
                const float s     = d * SCALE_LOG2E;       // log2-domain score
                const float mn    = fmaxf(m[g], s);
                const float alpha = exp2f(m[g] - mn);
                const float pw    = exp2f(s - mn);
                l[g] = l[g] * alpha + pw;
                acc[g].x = acc[g].x * alpha + pw * vx.x;
                acc[g].y = acc[g].y * alpha + pw * vx.y;
                acc[g].z = acc[g].z * alpha + pw * vx.z;
                acc[g].w = acc[g].w * alpha + pw * vx.w;
                m[g] = mn;
            }
        }
        kv = kn; vv = vn; p = pn;
    }

    // Reduce the 8 half-wave partials (4 waves x 2 halves) through LDS.
    __shared__ float sm[NG][8], sl[NG][8];
    __shared__ float4 sacc[NG][8][32];       // 16 KB
    const int hw = wave * 2 + half;
#pragma unroll
    for (int g = 0; g < NG; ++g) {
        if (ql == 0) { sm[g][hw] = m[g]; sl[g][hw] = l[g]; }
        sacc[g][hw][ql] = acc[g];
    }
    __syncthreads();

    const int g = wave;                      // wave w owns query-group g=w
    float M = -INFINITY;
#pragma unroll
    for (int j = 0; j < 8; ++j) M = fmaxf(M, sm[g][j]);
    float L = 0.f, w8[8];
#pragma unroll
    for (int j = 0; j < 8; ++j) {
        w8[j] = exp2f(sm[g][j] - M);         // exp2(-inf - M) = 0 for empty halves
        L += w8[j] * sl[g][j];
    }

    if (half == 0) {                         // lanes 0..31 write the 128 dims
        float4 o = make_float4(0.f, 0.f, 0.f, 0.f);
#pragma unroll
        for (int j = 0; j < 8; ++j) {
            const float4 a = sacc[g][j][ql];
            o.x += w8[j] * a.x; o.y += w8[j] * a.y;
            o.z += w8[j] * a.z; o.w += w8[j] * a.w;
        }
        const size_t pidx = ((size_t)(b * NKV + h) * NG + g) * NCH + c;
        if (ql == 0) { pml[pidx * 2] = M; pml[pidx * 2 + 1] = L; }
        *(float4*)(pacc + pidx * DH + ql * 4) = o;
    }
}

// Kernel 2: combine the <=8 chunk partials per (b, kv-head, g) with
// log-sum-exp rescaling and write the normalized output.
__global__ __launch_bounds__(256) void attn_combine_kernel(
    const int* __restrict__ live_counts,
    const float* __restrict__ pml,
    const float* __restrict__ pacc,
    float* __restrict__ out)
{
    const int h = blockIdx.x;                // kv head
    const int b = blockIdx.y;                // batch
    const int g = (int)threadIdx.x >> 6;     // wave -> query group
    const int lane = (int)threadIdx.x & 63;  // 64 lanes x float2 = 128 dims

    const int live = live_counts[b];
    const int nc = (live + CHUNK - 1) / CHUNK;   // only these were written
    const size_t pbase = ((size_t)(b * NKV + h) * NG + g) * NCH;

    float M = -INFINITY;
    float mv[NCH], lv[NCH];
    for (int cj = 0; cj < nc; ++cj) {
        mv[cj] = pml[(pbase + cj) * 2];
        lv[cj] = pml[(pbase + cj) * 2 + 1];
        M = fmaxf(M, mv[cj]);
    }
    float L = 0.f, w[NCH];
    for (int cj = 0; cj < nc; ++cj) {
        w[cj] = exp2f(mv[cj] - M);
        L += w[cj] * lv[cj];
    }
    const float inv = 1.f / L;

    float2 o = make_float2(0.f, 0.f);
    for (int cj = 0; cj < nc; ++cj) {
        const float2 a = *(const float2*)(pacc + (pbase + cj) * DH + lane * 2);
        o.x += w[cj] * a.x;
        o.y += w[cj] * a.y;
    }
    o.x *= inv; o.y *= inv;
    *(float2*)(out + (size_t)(b * NH + h * NG + g) * DH + lane * 2) = o;
}

extern "C" void kernel_launch(void* const* d_in, const int* in_sizes, int n_in,
                              void* d_out, int out_size, void* d_ws, size_t ws_size,
                              hipStream_t stream) {
    const float* q    = (const float*)d_in[0];
    const float* knew = (const float*)d_in[1];
    const float* vnew = (const float*)d_in[2];
    const float* kc   = (const float*)d_in[3];
    const float* vc   = (const float*)d_in[4];
    const int* base   = (const int*)d_in[5];
    const int* live   = (const int*)d_in[6];
    const int* slot   = (const int*)d_in[7];
    float* out = (float*)d_out;

    // Workspace: pml = 2 * (32*8*4*8) floats, pacc = (32*8*4*8)*128 floats
    // total ~4.3 MB
    float* pml  = (float*)d_ws;
    float* pacc = pml + (size_t)2 * NB * NKV * NG * NCH;

    dim3 grid1(NCH, NKV, NB);   // 2048 blocks
    attn_partial_kernel<<<grid1, 256, 0, stream>>>(q, knew, vnew, kc, vc,
                                                   base, live, slot, pml, pacc);
    dim3 grid2(NKV, NB);        // 256 blocks
    attn_combine_kernel<<<grid2, 256, 0, stream>>>(live, pml, pacc, out);
}

// Round 2
// 487.359 us; speedup vs baseline: 1.0564x; 1.0564x over previous
//
#include <hip/hip_runtime.h>
#include <math.h>

// Problem constants (from reference)
#define NB 32
#define NH 32
#define NKV 8
#define NG 4          // H / HKV
#define DH 128
#define MAXL 2048
#define CHUNK 128
#define NCH (MAXL / CHUNK)   // 16
#define ROWF (NKV * DH)      // floats between consecutive cache positions (1024)

// (1/sqrt(128)) * log2(e) so scores live in log2 domain (native v_exp_f32)
#define SCALE_LOG2E 0.12752966529379885f

// Single-instruction cross-lane adds via DPP (identity 0 for out-of-row lanes).
template <int CTRL>
__device__ __forceinline__ float dpp_add(float x) {
    int y = __builtin_amdgcn_update_dpp(0, __float_as_int(x), CTRL, 0xf, 0xf, false);
    return x + __int_as_float(y);
}
// After this, lane31 = sum(lanes 0..31), lane63 = sum(lanes 32..63).
__device__ __forceinline__ float half_reduce_sum(float d) {
    d = dpp_add<0x111>(d);   // row_shr:1
    d = dpp_add<0x112>(d);   // row_shr:2
    d = dpp_add<0x114>(d);   // row_shr:4
    d = dpp_add<0x118>(d);   // row_shr:8
    d = dpp_add<0x142>(d);   // row_bcast:15
    return d;
}

// Kernel 1: per-(batch, kv-head, 128-pos chunk) partial attention.
// Block = 256 threads = 4 waves; wave w owns positions [c*128+32w, +32).
// Lanes 0-31 / 32-63 handle one position each per iteration:
// 32 lanes x float4 = one 512B KV row slice, fully coalesced.
// Three phases (scores -> block softmax -> PV), no per-position serial chain.
__global__ __launch_bounds__(256) void attn_partial_kernel(
    const float* __restrict__ q,
    const float* __restrict__ knew,
    const float* __restrict__ vnew,
    const float* __restrict__ kcache,
    const float* __restrict__ vcache,
    const int* __restrict__ base_offsets,
    const int* __restrict__ live_counts,
    const int* __restrict__ slot_mapping,
    float* __restrict__ pml,    // [NB*NKV*NG*NCH][2]  (m, l)
    float* __restrict__ pacc)   // [NB*NKV*NG*NCH][DH] unnormalized acc
{
    const int c = blockIdx.x;   // chunk
    const int h = blockIdx.y;   // kv head
    const int b = blockIdx.z;   // batch

    const int live = live_counts[b];
    const int p0 = c * CHUNK;
    if (p0 >= live) return;     // block-uniform early exit

    const int base = base_offsets[b];
    const int rep  = slot_mapping[b] - base;   // position replaced by knew/vnew

    const int tid  = (int)threadIdx.x;
    const int wave = tid >> 6;
    const int lane = tid & 63;
    const int half = lane >> 5;
    const int ql   = lane & 31;

    __shared__ float  sc[NG][CHUNK];      // scores, then p-weights (2 KB)
    __shared__ float4 sacc[NG][8][32];    // half-wave PV partials (16 KB)

    // Q fragments for the 4 grouped query heads
    float4 qv[NG];
#pragma unroll
    for (int g = 0; g < NG; ++g)
        qv[g] = *(const float4*)(q + (size_t)(b * NH + h * NG + g) * DH + ql * 4);

    const float4 kn4 = *(const float4*)(knew + (size_t)(b * NKV + h) * DH + ql * 4);
    const float4 vn4 = *(const float4*)(vnew + (size_t)(b * NKV + h) * DH + ql * 4);

    const int lim = live - 1;
    const int pw0 = p0 + wave * 32;
    const float* kb = kcache + (size_t)base * ROWF + h * DH + ql * 4;
    const float* vb = vcache + (size_t)base * ROWF + h * DH + ql * 4;

    // ---- Phase 1: scores (streams K). Branch-free: clamped addresses,
    // dead positions get -inf. Iterations fully independent.
#pragma unroll
    for (int i = 0; i < 16; ++i) {
        const int p  = pw0 + 2 * i + half;
        const int pc = min(p, lim);
        float4 kk = *(const float4*)(kb + ((size_t)pc << 10));
        if (pc == rep) kk = kn4;          // virtual scatter of the new token
#pragma unroll
        for (int g = 0; g < NG; ++g) {
            float d = kk.x * qv[g].x + kk.y * qv[g].y +
                      kk.z * qv[g].z + kk.w * qv[g].w;
            d = half_reduce_sum(d);
            const float s = (p <= lim) ? d * SCALE_LOG2E : -INFINITY;
            if (ql == 31) sc[g][p - p0] = s;   // lanes 31 & 63 write pair
        }
    }
    __syncthreads();

    // ---- Phase 2: block softmax for the whole chunk; wave g owns group g.
    {
        const int g = wave;
        const float s0 = sc[g][lane];
        const float s1 = sc[g][64 + lane];
        float m = fmaxf(s0, s1);
#pragma unroll
        for (int off = 1; off < 64; off <<= 1)
            m = fmaxf(m, __shfl_xor(m, off));
        const float e0 = exp2f(s0 - m);
        const float e1 = exp2f(s1 - m);
        float l = e0 + e1;
#pragma unroll
        for (int off = 1; off < 64; off <<= 1)
            l += __shfl_xor(l, off);
        sc[g][lane]      = e0;           // weights back to LDS
        sc[g][64 + lane] = e1;
        if (lane == 0) {
            const size_t pidx = ((size_t)(b * NKV + h) * NG + g) * NCH + c;
            pml[pidx * 2]     = m;
            pml[pidx * 2 + 1] = l;
        }
    }
    __syncthreads();

    // ---- Phase 3: PV (streams V). Weights are broadcast LDS reads.
    float4 acc[NG];
#pragma unroll
    for (int g = 0; g < NG; ++g) acc[g] = make_float4(0.f, 0.f, 0.f, 0.f);

#pragma unroll
    for (int i = 0; i < 16; ++i) {
        const int p  = pw0 + 2 * i + half;
        const int pc = min(p, lim);
        float4 vv = *(const float4*)(vb + ((size_t)pc << 10));
        if (pc == rep) vv = vn4;
        const int pos = p - p0;
#pragma unroll
        for (int g = 0; g < NG; ++g) {
            const float w = sc[g][pos];   // 0 for dead positions
            acc[g].x += w * vv.x;
            acc[g].y += w * vv.y;
            acc[g].z += w * vv.z;
            acc[g].w += w * vv.w;
        }
    }

    // Combine the 8 half-wave partials (plain sums — shared m within block).
    const int hw = wave * 2 + half;
#pragma unroll
    for (int g = 0; g < NG; ++g)
        sacc[g][hw][ql] = acc[g];
    __syncthreads();

    if (half == 0) {                      // lanes 0..31 of wave g write group g
        const int g = wave;
        float4 o = make_float4(0.f, 0.f, 0.f, 0.f);
#pragma unroll
        for (int j = 0; j < 8; ++j) {
            const float4 a = sacc[g][j][ql];
            o.x += a.x; o.y += a.y; o.z += a.z; o.w += a.w;
        }
        const size_t pidx = ((size_t)(b * NKV + h) * NG + g) * NCH + c;
        *(float4*)(pacc + pidx * DH + ql * 4) = o;
    }
}

// Kernel 2: LSE-combine the <=16 chunk partials per (b, kv-head, group).
// No local arrays (avoids scratch); pml re-reads are L2-hot (128 KB total).
__global__ __launch_bounds__(256) void attn_combine_kernel(
    const int* __restrict__ live_counts,
    const float* __restrict__ pml,
    const float* __restrict__ pacc,
    float* __restrict__ out)
{
    const int h = blockIdx.x;
    const int b = blockIdx.y;
    const int g = (int)threadIdx.x >> 6;
    const int lane = (int)threadIdx.x & 63;   // 64 lanes x float2 = 128 dims

    const int live = live_counts[b];
    const int nc = (live + CHUNK - 1) / CHUNK;
    const size_t pbase = ((size_t)(b * NKV + h) * NG + g) * NCH;

    float M = -INFINITY;
    for (int cj = 0; cj < nc; ++cj)
        M = fmaxf(M, pml[(pbase + cj) * 2]);
    float L = 0.f;
    for (int cj = 0; cj < nc; ++cj)
        L += exp2f(pml[(pbase + cj) * 2] - M) * pml[(pbase + cj) * 2 + 1];
    float2 o = make_float2(0.f, 0.f);
    for (int cj = 0; cj < nc; ++cj) {
        const float w = exp2f(pml[(pbase + cj) * 2] - M);
        const float2 a = *(const float2*)(pacc + (pbase + cj) * DH + lane * 2);
        o.x += w * a.x;
        o.y += w * a.y;
    }
    const float inv = 1.f / L;
    o.x *= inv; o.y *= inv;
    *(float2*)(out + (size_t)(b * NH + h * NG + g) * DH + lane * 2) = o;
}

extern "C" void kernel_launch(void* const* d_in, const int* in_sizes, int n_in,
                              void* d_out, int out_size, void* d_ws, size_t ws_size,
                              hipStream_t stream) {
    const float* q    = (const float*)d_in[0];
    const float* knew = (const float*)d_in[1];
    const float* vnew = (const float*)d_in[2];
    const float* kc   = (const float*)d_in[3];
    const float* vc   = (const float*)d_in[4];
    const int* base   = (const int*)d_in[5];
    const int* live   = (const int*)d_in[6];
    const int* slot   = (const int*)d_in[7];
    float* out = (float*)d_out;

    // Workspace: pml = 2*(32*8*4*16) floats (128 KB), pacc = 16384*128 floats (8 MB)
    float* pml  = (float*)d_ws;
    float* pacc = pml + (size_t)2 * NB * NKV * NG * NCH;

    dim3 grid1(NCH, NKV, NB);   // 4096 blocks
    attn_partial_kernel<<<grid1, 256, 0, stream>>>(q, knew, vnew, kc, vc,
                                                   base, live, slot, pml, pacc);
    dim3 grid2(NKV, NB);        // 256 blocks
    attn_combine_kernel<<<grid2, 256, 0, stream>>>(live, pml, pacc, out);
}